// Round 2
// baseline (1768.719 us; speedup 1.0000x reference)
//
#include <hip/hip_runtime.h>
#include <cstddef>

#define Bb 8
#define Tt 24
#define Nn 512
#define Dd 128
#define Hh 8

// ---------------------------------------------------------------------------
// Generic tiled f32 GEMM body: C[M,N] = A[M,K] @ W[K,N] (+bias, +relu)
// 64x64 tile, BK=16, 256 threads, 4x4 per thread. All dims multiples of 64/16.
// ---------------------------------------------------------------------------
__device__ __forceinline__ void gemm_body(const float* __restrict__ A,
                                          const float* __restrict__ W,
                                          const float* __restrict__ bias,
                                          float* __restrict__ C,
                                          int N, int K,
                                          int m0, int n0, int relu)
{
  __shared__ float sA[16][65];
  __shared__ float sB[16][64];
  const int tid = threadIdx.x;
  const int tx = tid & 15, ty = tid >> 4;
  float acc[4][4] = {{0.f}};
  for (int k0 = 0; k0 < K; k0 += 16) {
#pragma unroll
    for (int i = 0; i < 4; ++i) {
      int idx = tid + i * 256;
      int m = idx >> 4, k = idx & 15;
      sA[k][m] = A[(size_t)(m0 + m) * K + (k0 + k)];
    }
#pragma unroll
    for (int i = 0; i < 4; ++i) {
      int idx = tid + i * 256;
      int k = idx >> 6, n = idx & 63;
      sB[k][n] = W[(size_t)(k0 + k) * N + (n0 + n)];
    }
    __syncthreads();
#pragma unroll
    for (int kk = 0; kk < 16; ++kk) {
      float a[4], b[4];
#pragma unroll
      for (int i = 0; i < 4; ++i) a[i] = sA[kk][ty * 4 + i];
#pragma unroll
      for (int j = 0; j < 4; ++j) b[j] = sB[kk][tx * 4 + j];
#pragma unroll
      for (int i = 0; i < 4; ++i)
#pragma unroll
        for (int j = 0; j < 4; ++j)
          acc[i][j] = fmaf(a[i], b[j], acc[i][j]);
    }
    __syncthreads();
  }
#pragma unroll
  for (int i = 0; i < 4; ++i) {
    int m = m0 + ty * 4 + i;
#pragma unroll
    for (int j = 0; j < 4; ++j) {
      int n = n0 + tx * 4 + j;
      float v = acc[i][j];
      if (bias) v += bias[n];
      if (relu) v = fmaxf(v, 0.f);
      C[(size_t)m * N + n] = v;
    }
  }
}

template <int RELU>
__global__ __launch_bounds__(256) void gemm_f32(const float* __restrict__ A,
                                                const float* __restrict__ W,
                                                const float* __restrict__ bias,
                                                float* __restrict__ C,
                                                int N, int K)
{
  gemm_body(A, W, bias, C, N, K, blockIdx.y * 64, blockIdx.x * 64, RELU);
}

// x1[bl,t] = graph[t] @ x[bl,t] : batched [512x512]@[512x128], bl local to chunk
__global__ __launch_bounds__(256) void gemm_graph(const float* __restrict__ graph,
                                                  const float* __restrict__ x,
                                                  float* __restrict__ x1)
{
  const int bt = blockIdx.z;
  const int t = bt % Tt;
  const float* A = graph + (size_t)t * Nn * Nn;
  const float* W = x + (size_t)bt * Nn * Dd;
  float* C = x1 + (size_t)bt * Nn * Dd;
  gemm_body(A, W, nullptr, C, Dd, Nn, blockIdx.y * 64, blockIdx.x * 64, 0);
}

// pw-GEMM fused with glo update: glo[m,:] = base[m,:] + att[m,:] * (A@W + bias) * scale
// N fixed = 128.
__global__ __launch_bounds__(256) void gemm_pwglo(const float* __restrict__ A,
                                                  const float* __restrict__ W,
                                                  const float* __restrict__ bias,
                                                  const float* __restrict__ att,
                                                  const float* __restrict__ base,
                                                  float* __restrict__ glo,
                                                  float scale, int K)
{
  __shared__ float sA[16][65];
  __shared__ float sB[16][64];
  const int tid = threadIdx.x;
  const int tx = tid & 15, ty = tid >> 4;
  const int m0 = blockIdx.y * 64, n0 = blockIdx.x * 64;
  float acc[4][4] = {{0.f}};
  for (int k0 = 0; k0 < K; k0 += 16) {
#pragma unroll
    for (int i = 0; i < 4; ++i) {
      int idx = tid + i * 256;
      int m = idx >> 4, k = idx & 15;
      sA[k][m] = A[(size_t)(m0 + m) * K + (k0 + k)];
    }
#pragma unroll
    for (int i = 0; i < 4; ++i) {
      int idx = tid + i * 256;
      int k = idx >> 6, n = idx & 63;
      sB[k][n] = W[(size_t)(k0 + k) * 128 + (n0 + n)];
    }
    __syncthreads();
#pragma unroll
    for (int kk = 0; kk < 16; ++kk) {
      float a[4], b[4];
#pragma unroll
      for (int i = 0; i < 4; ++i) a[i] = sA[kk][ty * 4 + i];
#pragma unroll
      for (int j = 0; j < 4; ++j) b[j] = sB[kk][tx * 4 + j];
#pragma unroll
      for (int i = 0; i < 4; ++i)
#pragma unroll
        for (int j = 0; j < 4; ++j)
          acc[i][j] = fmaf(a[i], b[j], acc[i][j]);
    }
    __syncthreads();
  }
#pragma unroll
  for (int i = 0; i < 4; ++i) {
    int m = m0 + ty * 4 + i;
#pragma unroll
    for (int j = 0; j < 4; ++j) {
      int n = n0 + tx * 4 + j;
      float pw = acc[i][j] + bias[n];
      size_t idx = (size_t)m * 128 + n;
      glo[idx] = base[idx] + att[idx] * pw * scale;
    }
  }
}

// ---------------------------------------------------------------------------
// Spatial stats: per (bt_local, h): kvs[16][16] = sum_n kn^T v ; ksum[16]
// ---------------------------------------------------------------------------
__global__ __launch_bounds__(256) void spatial_stats(const float* __restrict__ qkv,
                                                     float* __restrict__ kvs,
                                                     float* __restrict__ ksum)
{
  __shared__ float sk[512][16];
  __shared__ float sv[512][16];
  const int bt = blockIdx.x;
  const int h = blockIdx.y;
  const int tid = threadIdx.x;
#pragma unroll
  for (int r = 0; r < 2; ++r) {
    int n = tid * 2 + r;
    size_t base = ((size_t)bt * 512 + n) * 384;
    const float4* kp = (const float4*)(qkv + base + 128 + h * 16);
    const float4* vp = (const float4*)(qkv + base + 256 + h * 16);
    float4 k4[4];
    float s = 0.f;
#pragma unroll
    for (int i = 0; i < 4; ++i) {
      k4[i] = kp[i];
      s += k4[i].x * k4[i].x + k4[i].y * k4[i].y + k4[i].z * k4[i].z + k4[i].w * k4[i].w;
    }
    float inv = 1.f / fmaxf(sqrtf(s), 1e-12f);
    float4* skr = (float4*)&sk[n][0];
    float4* svr = (float4*)&sv[n][0];
#pragma unroll
    for (int i = 0; i < 4; ++i) {
      float4 t4 = k4[i];
      t4.x *= inv; t4.y *= inv; t4.z *= inv; t4.w *= inv;
      skr[i] = t4;
      svr[i] = vp[i];
    }
  }
  __syncthreads();
  const int m = tid >> 4, d = tid & 15;
  float acc = 0.f, ks = 0.f;
  for (int n = 0; n < 512; ++n) {
    float kn = sk[n][m];
    acc = fmaf(kn, sv[n][d], acc);
    if (d == 0) ks += kn;
  }
  size_t o = (size_t)bt * 8 + h;
  kvs[o * 256 + m * 16 + d] = acc;
  if (d == 0) ksum[o * 16 + m] = ks;
}

// ---------------------------------------------------------------------------
// Temporal stats: per (b_local, n): per h: kvt[16][16] = sum_t kn^T v ; ksum_t
// ---------------------------------------------------------------------------
__global__ __launch_bounds__(256) void temporal_stats(const float* __restrict__ qkv,
                                                      float* __restrict__ kvt,
                                                      float* __restrict__ ksum_t)
{
  __shared__ float sk[24][128];
  __shared__ float sv[24][128];
  __shared__ float sinv[24][8];
  const int nn = blockIdx.x, b = blockIdx.y;
  const int tid = threadIdx.x;
  for (int i = tid; i < 24 * 256; i += 256) {
    int t = i >> 8, c = i & 255;
    float val = qkv[(((size_t)(b * 24 + t) * 512) + nn) * 384 + 128 + c];
    if (c < 128) sk[t][c] = val;
    else sv[t][c - 128] = val;
  }
  __syncthreads();
  if (tid < 192) {
    int t = tid >> 3, h = tid & 7;
    float s = 0.f;
#pragma unroll
    for (int j = 0; j < 16; ++j) { float v = sk[t][h * 16 + j]; s += v * v; }
    sinv[t][h] = 1.f / fmaxf(sqrtf(s), 1e-12f);
  }
  __syncthreads();
  const int m = tid >> 4, d = tid & 15;
  size_t nb = (size_t)b * 512 + nn;
#pragma unroll
  for (int h = 0; h < 8; ++h) {
    float acc = 0.f, ks = 0.f;
#pragma unroll
    for (int t = 0; t < 24; ++t) {
      float kn = sk[t][h * 16 + m] * sinv[t][h];
      acc = fmaf(kn, sv[t][h * 16 + d], acc);
      if (d == 0) ks += kn;
    }
    kvt[(nb * 8 + h) * 256 + m * 16 + d] = acc;
    if (d == 0) ksum_t[(nb * 8 + h) * 16 + m] = ks;
  }
}

// ---------------------------------------------------------------------------
// Apply: per (b_local, n), loop t: out_cat[row, 0:128]=out_s, [128:256]=out_t
// ---------------------------------------------------------------------------
__global__ __launch_bounds__(256) void attn_apply(const float* __restrict__ qkv,
                                                  const float* __restrict__ kvs,
                                                  const float* __restrict__ ksum_s,
                                                  const float* __restrict__ kvt,
                                                  const float* __restrict__ ksum_t,
                                                  float* __restrict__ out_cat)
{
  __shared__ float s_kvt[8][256];
  __shared__ float s_kst[8][16];
  __shared__ float s_q[128];
  __shared__ float s_v[128];
  __shared__ float s_inv[8];
  const int nn = blockIdx.x, b = blockIdx.y;
  const int tid = threadIdx.x;
  const size_t nb = (size_t)b * 512 + nn;
  for (int i = tid; i < 2048; i += 256) s_kvt[i >> 8][i & 255] = kvt[nb * 2048 + i];
  if (tid < 128) s_kst[tid >> 4][tid & 15] = ksum_t[nb * 128 + tid];
  const int c = tid;
  const bool temporal = c >= 128;
  const int hh = (c & 127) >> 4;
  const int d = c & 15;
  for (int t = 0; t < 24; ++t) {
    size_t row = ((size_t)(b * 24 + t) * 512) + nn;
    __syncthreads();
    if (tid < 128) s_q[tid] = qkv[row * 384 + tid];
    else s_v[tid - 128] = qkv[row * 384 + 256 + (tid - 128)];
    __syncthreads();
    if (tid < 8) {
      float s = 0.f;
#pragma unroll
      for (int j = 0; j < 16; ++j) { float v = s_q[tid * 16 + j]; s += v * v; }
      s_inv[tid] = 1.f / fmaxf(sqrtf(s), 1e-12f);
    }
    __syncthreads();
    const float* Mm = temporal ? &s_kvt[hh][0]
                               : (kvs + ((size_t)(b * 24 + t) * 8 + hh) * 256);
    const float* Ks = temporal ? &s_kst[hh][0]
                               : (ksum_s + ((size_t)(b * 24 + t) * 8 + hh) * 16);
    const float cnt = temporal ? 24.f : 512.f;
    const float inv = s_inv[hh];
    float acc = 0.f, den = 0.f;
#pragma unroll
    for (int mI = 0; mI < 16; ++mI) {
      float qn = s_q[hh * 16 + mI] * inv;
      acc = fmaf(qn, Mm[mI * 16 + d], acc);
      den = fmaf(qn, Ks[mI], den);
    }
    float vv = s_v[hh * 16 + d];
    out_cat[row * 256 + c] = (acc + cnt * vv) / (den + cnt);
  }
}

// out = LN(a + b); one 64-lane wave per 128-elem row, 4 rows/block
__global__ __launch_bounds__(256) void layernorm2(const float* __restrict__ a,
                                                  const float* __restrict__ b,
                                                  const float* __restrict__ g,
                                                  const float* __restrict__ beta,
                                                  float* __restrict__ out)
{
  const int row = blockIdx.x * 4 + (threadIdx.x >> 6);
  const int lane = threadIdx.x & 63;
  const size_t base = (size_t)row * 128;
  float v0 = a[base + lane] + b[base + lane];
  float v1 = a[base + lane + 64] + b[base + lane + 64];
  float s = v0 + v1;
#pragma unroll
  for (int off = 32; off >= 1; off >>= 1) s += __shfl_xor(s, off);
  float mu = s * (1.f / 128.f);
  float d0 = v0 - mu, d1 = v1 - mu;
  float vs = d0 * d0 + d1 * d1;
#pragma unroll
  for (int off = 32; off >= 1; off >>= 1) vs += __shfl_xor(vs, off);
  float rstd = rsqrtf(vs * (1.f / 128.f) + 1e-5f);
  out[base + lane] = d0 * rstd * g[lane] + beta[lane];
  out[base + lane + 64] = d1 * rstd * g[lane + 64] + beta[lane + 64];
}

extern "C" void kernel_launch(void* const* d_in, const int* in_sizes, int n_in,
                              void* d_out, int out_size, void* d_ws, size_t ws_size,
                              hipStream_t stream)
{
  const float* x      = (const float*)d_in[0];
  const float* graph  = (const float*)d_in[1];
  const float* qkv_w0 = (const float*)d_in[2];
  const float* out_w0 = (const float*)d_in[3];
  const float* out_b0 = (const float*)d_in[4];
  const float* pw_w0  = (const float*)d_in[5];
  const float* pw_b0  = (const float*)d_in[6];
  const float* qkv_w1 = (const float*)d_in[7];
  const float* out_w1 = (const float*)d_in[8];
  const float* out_b1 = (const float*)d_in[9];
  const float* pw_w1  = (const float*)d_in[10];
  const float* pw_b1  = (const float*)d_in[11];
  const float* fc1_w  = (const float*)d_in[12];
  const float* fc1_b  = (const float*)d_in[13];
  const float* fc2_w  = (const float*)d_in[14];
  const float* fc2_b  = (const float*)d_in[15];
  const float* ln1_g  = (const float*)d_in[16];
  const float* ln1_b  = (const float*)d_in[17];
  const float* ln2_g  = (const float*)d_in[18];
  const float* ln2_b  = (const float*)d_in[19];
  float* out = (float*)d_out;

  // ---- choose batch-chunk size CB (largest that fits ws_size) -------------
  // per-b floats: rows 12288 * (qkv 384 + cat 256 + x1 128 + att0 128 + glo 128)
  //             + stats (kvs 24*8*256 + kss 24*8*16 + kvt 512*8*256 + kst 512*8*16)
  const size_t perb_floats = (size_t)12288 * 1024 + 49152 + 3072 + 1048576 + 65536;
  int CB = 8;
  while (CB > 1 && (size_t)CB * perb_floats * 4 > ws_size) CB >>= 1;

  const size_t Mc = (size_t)CB * Tt * Nn;   // rows per chunk
  float* wsf = (float*)d_ws;
  float* f_qkv  = wsf;                       // Mc*384  (f_h aliases first Mc*128)
  float* f_cat  = f_qkv  + Mc * 384;         // Mc*256  (also MLP hidden)
  float* f_x1   = f_cat  + Mc * 256;         // Mc*128  (att1 aliases)
  float* f_att0 = f_x1   + Mc * 128;         // Mc*128
  float* f_glo  = f_att0 + Mc * 128;         // Mc*128  (also MLP out)
  float* f_kvs  = f_glo  + Mc * 128;
  float* f_kss  = f_kvs  + (size_t)CB * Tt * Hh * 256;
  float* f_kvt  = f_kss  + (size_t)CB * Tt * Hh * 16;
  float* f_kst  = f_kvt  + (size_t)CB * Nn * Hh * 256;

  dim3 blk(256);
  const int MBc = (int)(Mc / 64);
  const int nchunk = Bb / CB;

  for (int c = 0; c < nchunk; ++c) {
    const size_t off = (size_t)c * CB * Tt * Nn * Dd;
    const float* xc = x + off;
    float* outc = out + off;

    // graph propagate: x1 = graph @ x (per local bt)
    gemm_graph<<<dim3(Dd / 64, Nn / 64, CB * Tt), blk, 0, stream>>>(graph, xc, f_x1);

    // ----- layer 0 (z = xc, c_in = xc, scale 1.0) -----
    gemm_f32<0><<<dim3(6, MBc), blk, 0, stream>>>(xc, qkv_w0, nullptr, f_qkv, 384, 128);
    spatial_stats<<<dim3(CB * Tt, Hh), blk, 0, stream>>>(f_qkv, f_kvs, f_kss);
    temporal_stats<<<dim3(Nn, CB), blk, 0, stream>>>(f_qkv, f_kvt, f_kst);
    attn_apply<<<dim3(Nn, CB), blk, 0, stream>>>(f_qkv, f_kvs, f_kss, f_kvt, f_kst, f_cat);
    gemm_f32<0><<<dim3(2, MBc), blk, 0, stream>>>(f_cat, out_w0, out_b0, f_att0, 128, 256);
    gemm_pwglo<<<dim3(2, MBc), blk, 0, stream>>>(xc, pw_w0, pw_b0, f_att0, xc, f_glo, 1.0f, 128);

    // ----- layer 1 (z = x1, c_in = att0, scale 0.01) -----
    gemm_f32<0><<<dim3(6, MBc), blk, 0, stream>>>(f_x1, qkv_w1, nullptr, f_qkv, 384, 128);
    spatial_stats<<<dim3(CB * Tt, Hh), blk, 0, stream>>>(f_qkv, f_kvs, f_kss);
    temporal_stats<<<dim3(Nn, CB), blk, 0, stream>>>(f_qkv, f_kvt, f_kst);
    attn_apply<<<dim3(Nn, CB), blk, 0, stream>>>(f_qkv, f_kvs, f_kss, f_kvt, f_kst, f_cat);
    float* f_att1 = f_x1;  // x1 consumed by L1 qkv GEMM; reuse region
    gemm_f32<0><<<dim3(2, MBc), blk, 0, stream>>>(f_cat, out_w1, out_b1, f_att1, 128, 256);
    gemm_pwglo<<<dim3(2, MBc), blk, 0, stream>>>(f_att0, pw_w1, pw_b1, f_att1, f_glo, f_glo, 0.01f, 128);

    // h = LN(x + x_glo); h aliases qkv region (dead)
    float* f_h = f_qkv;
    layernorm2<<<dim3((int)(Mc / 4)), blk, 0, stream>>>(xc, f_glo, ln1_g, ln1_b, f_h);
    // MLP: hid (cat region) = relu(h@fc1+b); mlp (glo region) = hid@fc2+b
    gemm_f32<1><<<dim3(4, MBc), blk, 0, stream>>>(f_h, fc1_w, fc1_b, f_cat, 256, 128);
    gemm_f32<0><<<dim3(2, MBc), blk, 0, stream>>>(f_cat, fc2_w, fc2_b, f_glo, 128, 256);
    // out = LN(h + mlp)
    layernorm2<<<dim3((int)(Mc / 4)), blk, 0, stream>>>(f_h, f_glo, ln2_g, ln2_b, outc);
  }

  (void)in_sizes; (void)n_in; (void)out_size;
}

// Round 3
// 973.508 us; speedup vs baseline: 1.8169x; 1.8169x over previous
//
#include <hip/hip_runtime.h>
#include <cstddef>

#define Bb 8
#define Tt 24
#define Nn 512
#define Dd 128
#define Hh 8

typedef unsigned short u16;
using short8 = __attribute__((ext_vector_type(8))) short;
using f32x4  = __attribute__((ext_vector_type(4))) float;

__device__ __forceinline__ float b2f(u16 u) {
  union { unsigned u; float f; } w; w.u = ((unsigned)u) << 16; return w.f;
}
__device__ __forceinline__ u16 f2b(float f) {
  union { float f; unsigned u; } w; w.f = f;
  unsigned r = w.u + 0x7FFFu + ((w.u >> 16) & 1u);
  return (u16)(r >> 16);
}

// ---------------------------------------------------------------------------
// bf16 MFMA GEMM: C[M,N] = A[M,K] @ B[K,N], B given transposed BT[N][K].
// 128x128 tile, BK=32, 256 threads = 4 waves (2x2 of 64x64).
// LDS layout [128 rows][32 k] bf16, byte addr ^= ((row&7)<<4) swizzle.
// Fragment layout (m89/m92-verified): A/B lane l: idx=l&15, k=(l>>4)*8+j;
// C/D: col=l&15, row=(l>>4)*4+reg.
// ---------------------------------------------------------------------------
template <int OUTBF16, int RELU, int PW>
__device__ __forceinline__ void gemm_mfma_body(
    const u16* __restrict__ A, const u16* __restrict__ BT,
    const float* __restrict__ bias, void* __restrict__ Cv,
    const u16* __restrict__ att, const float* __restrict__ base,
    float scale, int N, int K, int m0, int n0)
{
  __shared__ u16 sA[4096];
  __shared__ u16 sB[4096];
  const int tid = threadIdx.x;
  const int l = tid & 63, wid = tid >> 6;
  const int wm = (wid >> 1) << 6, wn = (wid & 1) << 6;
  f32x4 acc[4][4] = {};

  int a_off[4], b_off[4];
#pragma unroll
  for (int i = 0; i < 4; ++i) {
    int ra = wm + i * 16 + (l & 15);
    a_off[i] = ((ra << 6) + ((l >> 4) << 4)) ^ ((ra & 7) << 4);
    int rb = wn + i * 16 + (l & 15);
    b_off[i] = ((rb << 6) + ((l >> 4) << 4)) ^ ((rb & 7) << 4);
  }
  const int r0 = tid >> 2, s0 = tid & 3;
  const int r1 = r0 + 64;
  const int w0 = ((r0 << 6) + (s0 << 4)) ^ ((r0 & 7) << 4);
  const int w1 = ((r1 << 6) + (s0 << 4)) ^ ((r1 & 7) << 4);
  const size_t aR0 = (size_t)(m0 + r0) * K, aR1 = (size_t)(m0 + r1) * K;
  const size_t bR0 = (size_t)(n0 + r0) * K, bR1 = (size_t)(n0 + r1) * K;
  const int ks = s0 * 8;

  for (int k0 = 0; k0 < K; k0 += 32) {
    short8 a0 = *(const short8*)(A + aR0 + k0 + ks);
    short8 a1 = *(const short8*)(A + aR1 + k0 + ks);
    short8 b0 = *(const short8*)(BT + bR0 + k0 + ks);
    short8 b1 = *(const short8*)(BT + bR1 + k0 + ks);
    __syncthreads();
    *(short8*)((char*)sA + w0) = a0;
    *(short8*)((char*)sA + w1) = a1;
    *(short8*)((char*)sB + w0) = b0;
    *(short8*)((char*)sB + w1) = b1;
    __syncthreads();
    short8 af[4], bf_[4];
#pragma unroll
    for (int i = 0; i < 4; ++i) {
      af[i]  = *(const short8*)((const char*)sA + a_off[i]);
      bf_[i] = *(const short8*)((const char*)sB + b_off[i]);
    }
#pragma unroll
    for (int mi = 0; mi < 4; ++mi)
#pragma unroll
      for (int ni = 0; ni < 4; ++ni)
        acc[mi][ni] = __builtin_amdgcn_mfma_f32_16x16x32_bf16(
            af[mi], bf_[ni], acc[mi][ni], 0, 0, 0);
  }

  const int cr = (l >> 4) << 2;
  const int cc = l & 15;
#pragma unroll
  for (int mi = 0; mi < 4; ++mi) {
    int rowb = m0 + wm + mi * 16 + cr;
#pragma unroll
    for (int ni = 0; ni < 4; ++ni) {
      int col = n0 + wn + ni * 16 + cc;
      float bb = bias ? bias[col] : 0.f;
#pragma unroll
      for (int r = 0; r < 4; ++r) {
        float v = acc[mi][ni][r] + bb;
        if (RELU) v = fmaxf(v, 0.f);
        size_t idx = (size_t)(rowb + r) * N + col;
        if (PW) {
          ((float*)Cv)[idx] = base[idx] + b2f(att[idx]) * v * scale;
        } else if (OUTBF16) {
          ((u16*)Cv)[idx] = f2b(v);
        } else {
          ((float*)Cv)[idx] = v;
        }
      }
    }
  }
}

template <int OUTBF16, int RELU, int PW>
__global__ __launch_bounds__(256) void gemm_mfma_k(
    const u16* __restrict__ A, const u16* __restrict__ BT,
    const float* __restrict__ bias, void* __restrict__ C,
    const u16* __restrict__ att, const float* __restrict__ base,
    float scale, int N, int K)
{
  gemm_mfma_body<OUTBF16, RELU, PW>(A, BT, bias, C, att, base, scale, N, K,
                                    blockIdx.y * 128, blockIdx.x * 128);
}

// x1[bt] = graph[t] @ x[bt] : A=graph bf16 [512][512], BT=xT [128][512]
__global__ __launch_bounds__(256) void gemm_mfma_graph(
    const u16* __restrict__ g, const u16* __restrict__ xT, u16* __restrict__ x1)
{
  const int bt = blockIdx.z, t = bt % Tt;
  gemm_mfma_body<1, 0, 0>(g + (size_t)t * Nn * Nn, xT + (size_t)bt * Dd * Nn,
                          nullptr, x1 + (size_t)bt * Nn * Dd, nullptr, nullptr,
                          0.f, Dd, Nn, blockIdx.y * 128, 0);
}

// ---------------------------------------------------------------------------
// convert f32 -> bf16 (8 elems/thread)
// ---------------------------------------------------------------------------
__global__ __launch_bounds__(256) void cvt_f32_bf16(const float* __restrict__ src,
                                                    u16* __restrict__ dst, size_t n8)
{
  size_t i = (size_t)blockIdx.x * 256 + threadIdx.x;
  if (i >= n8) return;
  const float4* s = (const float4*)src;
  float4 u = s[i * 2], v = s[i * 2 + 1];
  short8 o;
  o[0] = (short)f2b(u.x); o[1] = (short)f2b(u.y);
  o[2] = (short)f2b(u.z); o[3] = (short)f2b(u.w);
  o[4] = (short)f2b(v.x); o[5] = (short)f2b(v.y);
  o[6] = (short)f2b(v.z); o[7] = (short)f2b(v.w);
  *(short8*)(dst + i * 8) = o;
}

// transpose + convert: src f32 [R][C] -> dst bf16 [C][R]; z batches
__global__ __launch_bounds__(256) void transpose_cvt(const float* __restrict__ src,
                                                     u16* __restrict__ dst,
                                                     int R, int C)
{
  __shared__ u16 tile[64][65];
  const int tid = threadIdx.x;
  src += (size_t)blockIdx.z * R * C;
  dst += (size_t)blockIdx.z * R * C;
  const int c0 = blockIdx.x * 64, r0 = blockIdx.y * 64;
  const int tx = tid & 63, ty = tid >> 6;
#pragma unroll
  for (int i = 0; i < 64; i += 4)
    tile[ty + i][tx] = f2b(src[(size_t)(r0 + ty + i) * C + c0 + tx]);
  __syncthreads();
#pragma unroll
  for (int i = 0; i < 64; i += 4)
    dst[(size_t)(c0 + ty + i) * R + r0 + tx] = tile[tx][ty + i];
}

// ---------------------------------------------------------------------------
// Spatial stats: per (bt_local, h): kvs[16][16] = sum_n kn^T v ; ksum[16]
// ---------------------------------------------------------------------------
__global__ __launch_bounds__(256) void spatial_stats(const u16* __restrict__ qkv,
                                                     float* __restrict__ kvs,
                                                     float* __restrict__ ksum)
{
  __shared__ float sk[512][16];
  __shared__ float sv[512][16];
  const int bt = blockIdx.x;
  const int h = blockIdx.y;
  const int tid = threadIdx.x;
#pragma unroll
  for (int r = 0; r < 2; ++r) {
    int n = tid * 2 + r;
    size_t base = ((size_t)bt * 512 + n) * 384;
    const short8* kp = (const short8*)(qkv + base + 128 + h * 16);
    const short8* vp = (const short8*)(qkv + base + 256 + h * 16);
    short8 kA = kp[0], kB = kp[1], vA = vp[0], vB = vp[1];
    float kf[16], vf[16];
#pragma unroll
    for (int j = 0; j < 8; ++j) {
      kf[j] = b2f((u16)kA[j]); kf[j + 8] = b2f((u16)kB[j]);
      vf[j] = b2f((u16)vA[j]); vf[j + 8] = b2f((u16)vB[j]);
    }
    float s = 0.f;
#pragma unroll
    for (int j = 0; j < 16; ++j) s += kf[j] * kf[j];
    float inv = 1.f / fmaxf(sqrtf(s), 1e-12f);
#pragma unroll
    for (int j = 0; j < 16; ++j) { sk[n][j] = kf[j] * inv; sv[n][j] = vf[j]; }
  }
  __syncthreads();
  const int m = tid >> 4, d = tid & 15;
  float acc = 0.f, ks = 0.f;
  for (int n = 0; n < 512; ++n) {
    float kn = sk[n][m];
    acc = fmaf(kn, sv[n][d], acc);
    if (d == 0) ks += kn;
  }
  size_t o = (size_t)bt * 8 + h;
  kvs[o * 256 + m * 16 + d] = acc;
  if (d == 0) ksum[o * 16 + m] = ks;
}

// ---------------------------------------------------------------------------
// Temporal stats: per (b_local, n): per h: kvt[16][16] = sum_t kn^T v ; ksum_t
// ---------------------------------------------------------------------------
__global__ __launch_bounds__(256) void temporal_stats(const u16* __restrict__ qkv,
                                                      float* __restrict__ kvt,
                                                      float* __restrict__ ksum_t)
{
  __shared__ float sk[24][128];
  __shared__ float sv[24][128];
  __shared__ float sinv[24][8];
  const int nn = blockIdx.x, b = blockIdx.y;
  const int tid = threadIdx.x;
  for (int i = tid; i < 24 * 256; i += 256) {
    int t = i >> 8, c = i & 255;
    float val = b2f(qkv[(((size_t)(b * 24 + t) * 512) + nn) * 384 + 128 + c]);
    if (c < 128) sk[t][c] = val;
    else sv[t][c - 128] = val;
  }
  __syncthreads();
  if (tid < 192) {
    int t = tid >> 3, h = tid & 7;
    float s = 0.f;
#pragma unroll
    for (int j = 0; j < 16; ++j) { float v = sk[t][h * 16 + j]; s += v * v; }
    sinv[t][h] = 1.f / fmaxf(sqrtf(s), 1e-12f);
  }
  __syncthreads();
  const int m = tid >> 4, d = tid & 15;
  size_t nb = (size_t)b * 512 + nn;
#pragma unroll
  for (int h = 0; h < 8; ++h) {
    float acc = 0.f, ks = 0.f;
#pragma unroll
    for (int t = 0; t < 24; ++t) {
      float kn = sk[t][h * 16 + m] * sinv[t][h];
      acc = fmaf(kn, sv[t][h * 16 + d], acc);
      if (d == 0) ks += kn;
    }
    kvt[(nb * 8 + h) * 256 + m * 16 + d] = acc;
    if (d == 0) ksum_t[(nb * 8 + h) * 16 + m] = ks;
  }
}

// ---------------------------------------------------------------------------
// Apply: per (b_local, n), loop t: cat[row,0:128]=out_s, [128:256]=out_t (bf16)
// ---------------------------------------------------------------------------
__global__ __launch_bounds__(256) void attn_apply(const u16* __restrict__ qkv,
                                                  const float* __restrict__ kvs,
                                                  const float* __restrict__ ksum_s,
                                                  const float* __restrict__ kvt,
                                                  const float* __restrict__ ksum_t,
                                                  u16* __restrict__ out_cat)
{
  __shared__ float s_kvt[8][256];
  __shared__ float s_kst[8][16];
  __shared__ float s_q[128];
  __shared__ float s_v[128];
  __shared__ float s_inv[8];
  const int nn = blockIdx.x, b = blockIdx.y;
  const int tid = threadIdx.x;
  const size_t nb = (size_t)b * 512 + nn;
  for (int i = tid; i < 2048; i += 256) s_kvt[i >> 8][i & 255] = kvt[nb * 2048 + i];
  if (tid < 128) s_kst[tid >> 4][tid & 15] = ksum_t[nb * 128 + tid];
  const int c = tid;
  const bool temporal = c >= 128;
  const int hh = (c & 127) >> 4;
  const int d = c & 15;
  for (int t = 0; t < 24; ++t) {
    size_t row = ((size_t)(b * 24 + t) * 512) + nn;
    __syncthreads();
    if (tid < 128) s_q[tid] = b2f(qkv[row * 384 + tid]);
    else s_v[tid - 128] = b2f(qkv[row * 384 + 256 + (tid - 128)]);
    __syncthreads();
    if (tid < 8) {
      float s = 0.f;
#pragma unroll
      for (int j = 0; j < 16; ++j) { float v = s_q[tid * 16 + j]; s += v * v; }
      s_inv[tid] = 1.f / fmaxf(sqrtf(s), 1e-12f);
    }
    __syncthreads();
    const float* Mm = temporal ? &s_kvt[hh][0]
                               : (kvs + ((size_t)(b * 24 + t) * 8 + hh) * 256);
    const float* Ks = temporal ? &s_kst[hh][0]
                               : (ksum_s + ((size_t)(b * 24 + t) * 8 + hh) * 16);
    const float cnt = temporal ? 24.f : 512.f;
    const float inv = s_inv[hh];
    float acc = 0.f, den = 0.f;
#pragma unroll
    for (int mI = 0; mI < 16; ++mI) {
      float qn = s_q[hh * 16 + mI] * inv;
      acc = fmaf(qn, Mm[mI * 16 + d], acc);
      den = fmaf(qn, Ks[mI], den);
    }
    float vv = s_v[hh * 16 + d];
    out_cat[row * 256 + c] = f2b((acc + cnt * vv) / (den + cnt));
  }
}

// out = LN(a + b); one wave per 128-elem row; optional bf16 copy
__global__ __launch_bounds__(256) void layernorm2(const float* __restrict__ a,
                                                  const float* __restrict__ b,
                                                  const float* __restrict__ g,
                                                  const float* __restrict__ beta,
                                                  float* __restrict__ out32,
                                                  u16* __restrict__ out16)
{
  const int row = blockIdx.x * 4 + (threadIdx.x >> 6);
  const int lane = threadIdx.x & 63;
  const size_t base = (size_t)row * 128;
  float v0 = a[base + lane] + b[base + lane];
  float v1 = a[base + lane + 64] + b[base + lane + 64];
  float s = v0 + v1;
#pragma unroll
  for (int off = 32; off >= 1; off >>= 1) s += __shfl_xor(s, off);
  float mu = s * (1.f / 128.f);
  float d0 = v0 - mu, d1 = v1 - mu;
  float vs = d0 * d0 + d1 * d1;
#pragma unroll
  for (int off = 32; off >= 1; off >>= 1) vs += __shfl_xor(vs, off);
  float rstd = rsqrtf(vs * (1.f / 128.f) + 1e-5f);
  float y0 = d0 * rstd * g[lane] + beta[lane];
  float y1 = d1 * rstd * g[lane + 64] + beta[lane + 64];
  out32[base + lane] = y0;
  out32[base + lane + 64] = y1;
  if (out16) {
    out16[base + lane] = f2b(y0);
    out16[base + lane + 64] = f2b(y1);
  }
}

extern "C" void kernel_launch(void* const* d_in, const int* in_sizes, int n_in,
                              void* d_out, int out_size, void* d_ws, size_t ws_size,
                              hipStream_t stream)
{
  const float* x      = (const float*)d_in[0];
  const float* graph  = (const float*)d_in[1];
  const float* qkv_w0 = (const float*)d_in[2];
  const float* out_w0 = (const float*)d_in[3];
  const float* out_b0 = (const float*)d_in[4];
  const float* pw_w0  = (const float*)d_in[5];
  const float* pw_b0  = (const float*)d_in[6];
  const float* qkv_w1 = (const float*)d_in[7];
  const float* out_w1 = (const float*)d_in[8];
  const float* out_b1 = (const float*)d_in[9];
  const float* pw_w1  = (const float*)d_in[10];
  const float* pw_b1  = (const float*)d_in[11];
  const float* fc1_w  = (const float*)d_in[12];
  const float* fc1_b  = (const float*)d_in[13];
  const float* fc2_w  = (const float*)d_in[14];
  const float* fc2_b  = (const float*)d_in[15];
  const float* ln1_g  = (const float*)d_in[16];
  const float* ln1_b  = (const float*)d_in[17];
  const float* ln2_g  = (const float*)d_in[18];
  const float* ln2_b  = (const float*)d_in[19];
  float* out = (float*)d_out;

  auto al = [](size_t v) { return (v + 255) & ~(size_t)255; };
  const size_t Rb = 12288;  // rows per batch element
  // fixed: graph bf16 + 8 transposed weights
  const size_t fixed = al((size_t)Tt * Nn * Nn * 2) + 2 * al((size_t)384 * 128 * 2)
                     + 2 * al((size_t)128 * 256 * 2) + 2 * al((size_t)128 * 128 * 2)
                     + al((size_t)256 * 128 * 2) + al((size_t)128 * 256 * 2);
  const size_t perb = al(Rb * 768) + al(Rb * 512) + 4 * al(Rb * 256) + al(Rb * 512)
                    + al((size_t)Tt * 8 * 256 * 4) + al((size_t)Tt * 8 * 16 * 4)
                    + al((size_t)Nn * 8 * 256 * 4) + al((size_t)Nn * 8 * 16 * 4);
  int CB = 8;
  while (CB > 1 && fixed + (size_t)CB * perb > ws_size) CB >>= 1;
  const size_t Mc = (size_t)CB * Rb;

  char* cur = (char*)d_ws;
  auto alloc = [&](size_t bytes) { char* p = cur; cur += (bytes + 255) & ~(size_t)255; return p; };
  u16* g_b16 = (u16*)alloc((size_t)Tt * Nn * Nn * 2);
  u16* qkvT0 = (u16*)alloc((size_t)384 * 128 * 2);
  u16* qkvT1 = (u16*)alloc((size_t)384 * 128 * 2);
  u16* outT0 = (u16*)alloc((size_t)128 * 256 * 2);
  u16* outT1 = (u16*)alloc((size_t)128 * 256 * 2);
  u16* pwT0  = (u16*)alloc((size_t)128 * 128 * 2);
  u16* pwT1  = (u16*)alloc((size_t)128 * 128 * 2);
  u16* fc1T  = (u16*)alloc((size_t)256 * 128 * 2);
  u16* fc2T  = (u16*)alloc((size_t)128 * 256 * 2);
  u16* qkvb  = (u16*)alloc(Mc * 768);          // reused as h32+h16 later
  u16* catb  = (u16*)alloc(Mc * 512);          // cat / MLP hidden
  u16* x1b   = (u16*)alloc(Mc * 256);          // x1 / att1
  u16* att0  = (u16*)alloc(Mc * 256);
  u16* xb    = (u16*)alloc(Mc * 256);
  u16* xT    = (u16*)alloc(Mc * 256);
  float* glo = (float*)alloc(Mc * 512);        // glo / MLP out
  float* kvs = (float*)alloc((size_t)CB * Tt * 8 * 256 * 4);
  float* kss = (float*)alloc((size_t)CB * Tt * 8 * 16 * 4);
  float* kvt = (float*)alloc((size_t)CB * Nn * 8 * 256 * 4);
  float* kst = (float*)alloc((size_t)CB * Nn * 8 * 16 * 4);

  dim3 blk(256);
  // one-time conversions
  cvt_f32_bf16<<<dim3((Tt * Nn * Nn / 8 + 255) / 256), blk, 0, stream>>>(
      graph, g_b16, (size_t)Tt * Nn * Nn / 8);
  transpose_cvt<<<dim3(6, 2, 1), blk, 0, stream>>>(qkv_w0, qkvT0, 128, 384);
  transpose_cvt<<<dim3(6, 2, 1), blk, 0, stream>>>(qkv_w1, qkvT1, 128, 384);
  transpose_cvt<<<dim3(2, 4, 1), blk, 0, stream>>>(out_w0, outT0, 256, 128);
  transpose_cvt<<<dim3(2, 4, 1), blk, 0, stream>>>(out_w1, outT1, 256, 128);
  transpose_cvt<<<dim3(2, 2, 1), blk, 0, stream>>>(pw_w0, pwT0, 128, 128);
  transpose_cvt<<<dim3(2, 2, 1), blk, 0, stream>>>(pw_w1, pwT1, 128, 128);
  transpose_cvt<<<dim3(4, 2, 1), blk, 0, stream>>>(fc1_w, fc1T, 128, 256);
  transpose_cvt<<<dim3(2, 4, 1), blk, 0, stream>>>(fc2_w, fc2T, 256, 128);

  const int MB = (int)(Mc / 128);   // 96*CB row-tiles
  const int nchunk = Bb / CB;
  for (int c = 0; c < nchunk; ++c) {
    const size_t off = (size_t)c * Mc * 128;
    const float* xc = x + off;
    float* outc = out + off;

    cvt_f32_bf16<<<dim3((unsigned)(Mc * 16 / 256)), blk, 0, stream>>>(xc, xb, Mc * 16);
    transpose_cvt<<<dim3(2, 8, CB * Tt), blk, 0, stream>>>(xc, xT, 512, 128);
    gemm_mfma_graph<<<dim3(1, 4, CB * Tt), blk, 0, stream>>>(g_b16, xT, x1b);

    // ----- layer 0 -----
    gemm_mfma_k<1, 0, 0><<<dim3(3, MB), blk, 0, stream>>>(
        xb, qkvT0, nullptr, qkvb, nullptr, nullptr, 0.f, 384, 128);
    spatial_stats<<<dim3(CB * Tt, Hh), blk, 0, stream>>>(qkvb, kvs, kss);
    temporal_stats<<<dim3(Nn, CB), blk, 0, stream>>>(qkvb, kvt, kst);
    attn_apply<<<dim3(Nn, CB), blk, 0, stream>>>(qkvb, kvs, kss, kvt, kst, catb);
    gemm_mfma_k<1, 0, 0><<<dim3(1, MB), blk, 0, stream>>>(
        catb, outT0, out_b0, att0, nullptr, nullptr, 0.f, 128, 256);
    gemm_mfma_k<0, 0, 1><<<dim3(1, MB), blk, 0, stream>>>(
        xb, pwT0, pw_b0, glo, att0, xc, 1.0f, 128, 128);

    // ----- layer 1 -----
    gemm_mfma_k<1, 0, 0><<<dim3(3, MB), blk, 0, stream>>>(
        x1b, qkvT1, nullptr, qkvb, nullptr, nullptr, 0.f, 384, 128);
    spatial_stats<<<dim3(CB * Tt, Hh), blk, 0, stream>>>(qkvb, kvs, kss);
    temporal_stats<<<dim3(Nn, CB), blk, 0, stream>>>(qkvb, kvt, kst);
    attn_apply<<<dim3(Nn, CB), blk, 0, stream>>>(qkvb, kvs, kss, kvt, kst, catb);
    u16* att1 = x1b;  // x1 consumed; reuse
    gemm_mfma_k<1, 0, 0><<<dim3(1, MB), blk, 0, stream>>>(
        catb, outT1, out_b1, att1, nullptr, nullptr, 0.f, 128, 256);
    gemm_mfma_k<0, 0, 1><<<dim3(1, MB), blk, 0, stream>>>(
        att0, pwT1, pw_b1, glo, att1, glo, 0.01f, 128, 128);

    // h = LN(x + glo) -> h32 (+h16); both alias dead qkv region
    float* h32 = (float*)qkvb;
    u16* h16 = (u16*)((char*)qkvb + Mc * 512);
    layernorm2<<<dim3((unsigned)(Mc / 4)), blk, 0, stream>>>(xc, glo, ln1_g, ln1_b, h32, h16);
    // MLP
    gemm_mfma_k<1, 1, 0><<<dim3(2, MB), blk, 0, stream>>>(
        h16, fc1T, fc1_b, catb, nullptr, nullptr, 0.f, 256, 128);
    gemm_mfma_k<0, 0, 0><<<dim3(1, MB), blk, 0, stream>>>(
        catb, fc2T, fc2_b, glo, nullptr, nullptr, 0.f, 128, 256);
    layernorm2<<<dim3((unsigned)(Mc / 4)), blk, 0, stream>>>(h32, glo, ln2_g, ln2_b, outc, nullptr);
  }

  (void)in_sizes; (void)n_in; (void)out_size;
}

// Round 4
// 867.066 us; speedup vs baseline: 2.0399x; 1.1228x over previous
//
#include <hip/hip_runtime.h>
#include <cstddef>

#define Bb 8
#define Tt 24
#define Nn 512
#define Dd 128
#define Hh 8

typedef unsigned short u16;
using short8 = __attribute__((ext_vector_type(8))) short;
using f32x4  = __attribute__((ext_vector_type(4))) float;

__device__ __forceinline__ float b2f(u16 u) {
  union { unsigned u; float f; } w; w.u = ((unsigned)u) << 16; return w.f;
}
__device__ __forceinline__ u16 f2b(float f) {
  union { float f; unsigned u; } w; w.f = f;
  unsigned r = w.u + 0x7FFFu + ((w.u >> 16) & 1u);
  return (u16)(r >> 16);
}

// ---------------------------------------------------------------------------
// bf16 MFMA GEMM: C[M,N] = A[M,K] @ B[K,N], B given transposed BT[N][K].
// 128x128 tile, BK=32, 256 threads = 4 waves (2x2 of 64x64).
// LDS layout [128 rows][32 k] bf16, byte addr ^= ((row&7)<<4) swizzle.
// ---------------------------------------------------------------------------
template <int OUTBF16, int RELU, int PW>
__device__ __forceinline__ void gemm_mfma_body(
    const u16* __restrict__ A, const u16* __restrict__ BT,
    const float* __restrict__ bias, void* __restrict__ Cv,
    const u16* __restrict__ att, const float* __restrict__ base,
    float scale, int N, int K, int m0, int n0)
{
  __shared__ u16 sA[4096];
  __shared__ u16 sB[4096];
  const int tid = threadIdx.x;
  const int l = tid & 63, wid = tid >> 6;
  const int wm = (wid >> 1) << 6, wn = (wid & 1) << 6;
  f32x4 acc[4][4] = {};

  int a_off[4], b_off[4];
#pragma unroll
  for (int i = 0; i < 4; ++i) {
    int ra = wm + i * 16 + (l & 15);
    a_off[i] = ((ra << 6) + ((l >> 4) << 4)) ^ ((ra & 7) << 4);
    int rb = wn + i * 16 + (l & 15);
    b_off[i] = ((rb << 6) + ((l >> 4) << 4)) ^ ((rb & 7) << 4);
  }
  const int r0 = tid >> 2, s0 = tid & 3;
  const int r1 = r0 + 64;
  const int w0 = ((r0 << 6) + (s0 << 4)) ^ ((r0 & 7) << 4);
  const int w1 = ((r1 << 6) + (s0 << 4)) ^ ((r1 & 7) << 4);
  const size_t aR0 = (size_t)(m0 + r0) * K, aR1 = (size_t)(m0 + r1) * K;
  const size_t bR0 = (size_t)(n0 + r0) * K, bR1 = (size_t)(n0 + r1) * K;
  const int ks = s0 * 8;

  for (int k0 = 0; k0 < K; k0 += 32) {
    short8 a0 = *(const short8*)(A + aR0 + k0 + ks);
    short8 a1 = *(const short8*)(A + aR1 + k0 + ks);
    short8 b0 = *(const short8*)(BT + bR0 + k0 + ks);
    short8 b1 = *(const short8*)(BT + bR1 + k0 + ks);
    __syncthreads();
    *(short8*)((char*)sA + w0) = a0;
    *(short8*)((char*)sA + w1) = a1;
    *(short8*)((char*)sB + w0) = b0;
    *(short8*)((char*)sB + w1) = b1;
    __syncthreads();
    short8 af[4], bf_[4];
#pragma unroll
    for (int i = 0; i < 4; ++i) {
      af[i]  = *(const short8*)((const char*)sA + a_off[i]);
      bf_[i] = *(const short8*)((const char*)sB + b_off[i]);
    }
#pragma unroll
    for (int mi = 0; mi < 4; ++mi)
#pragma unroll
      for (int ni = 0; ni < 4; ++ni)
        acc[mi][ni] = __builtin_amdgcn_mfma_f32_16x16x32_bf16(
            af[mi], bf_[ni], acc[mi][ni], 0, 0, 0);
  }

  const int cr = (l >> 4) << 2;
  const int cc = l & 15;
#pragma unroll
  for (int mi = 0; mi < 4; ++mi) {
    int rowb = m0 + wm + mi * 16 + cr;
#pragma unroll
    for (int ni = 0; ni < 4; ++ni) {
      int col = n0 + wn + ni * 16 + cc;
      float bb = bias ? bias[col] : 0.f;
#pragma unroll
      for (int r = 0; r < 4; ++r) {
        float v = acc[mi][ni][r] + bb;
        if (RELU) v = fmaxf(v, 0.f);
        size_t idx = (size_t)(rowb + r) * N + col;
        if (PW) {
          ((float*)Cv)[idx] = base[idx] + b2f(att[idx]) * v * scale;
        } else if (OUTBF16) {
          ((u16*)Cv)[idx] = f2b(v);
        } else {
          ((float*)Cv)[idx] = v;
        }
      }
    }
  }
}

template <int OUTBF16, int RELU, int PW>
__global__ __launch_bounds__(256) void gemm_mfma_k(
    const u16* __restrict__ A, const u16* __restrict__ BT,
    const float* __restrict__ bias, void* __restrict__ C,
    const u16* __restrict__ att, const float* __restrict__ base,
    float scale, int N, int K)
{
  gemm_mfma_body<OUTBF16, RELU, PW>(A, BT, bias, C, att, base, scale, N, K,
                                    blockIdx.y * 128, blockIdx.x * 128);
}

// x1[bt] = graph[t] @ x[bt] : A=graph bf16 [512][512], BT=xT [128][512]
__global__ __launch_bounds__(256) void gemm_mfma_graph(
    const u16* __restrict__ g, const u16* __restrict__ xT, u16* __restrict__ x1)
{
  const int bt = blockIdx.z, t = bt % Tt;
  gemm_mfma_body<1, 0, 0>(g + (size_t)t * Nn * Nn, xT + (size_t)bt * Dd * Nn,
                          nullptr, x1 + (size_t)bt * Nn * Dd, nullptr, nullptr,
                          0.f, Dd, Nn, blockIdx.y * 128, 0);
}

// ---------------------------------------------------------------------------
// convert f32 -> bf16 (8 elems/thread)
// ---------------------------------------------------------------------------
__global__ __launch_bounds__(256) void cvt_f32_bf16(const float* __restrict__ src,
                                                    u16* __restrict__ dst, size_t n8)
{
  size_t i = (size_t)blockIdx.x * 256 + threadIdx.x;
  if (i >= n8) return;
  const float4* s = (const float4*)src;
  float4 u = s[i * 2], v = s[i * 2 + 1];
  short8 o;
  o[0] = (short)f2b(u.x); o[1] = (short)f2b(u.y);
  o[2] = (short)f2b(u.z); o[3] = (short)f2b(u.w);
  o[4] = (short)f2b(v.x); o[5] = (short)f2b(v.y);
  o[6] = (short)f2b(v.z); o[7] = (short)f2b(v.w);
  *(short8*)(dst + i * 8) = o;
}

// transpose + convert: src f32 [R][C] -> dst bf16 [C][R]; z batches
__global__ __launch_bounds__(256) void transpose_cvt(const float* __restrict__ src,
                                                     u16* __restrict__ dst,
                                                     int R, int C)
{
  __shared__ u16 tile[64][65];
  const int tid = threadIdx.x;
  src += (size_t)blockIdx.z * R * C;
  dst += (size_t)blockIdx.z * R * C;
  const int c0 = blockIdx.x * 64, r0 = blockIdx.y * 64;
  const int tx = tid & 63, ty = tid >> 6;
#pragma unroll
  for (int i = 0; i < 64; i += 4)
    tile[ty + i][tx] = f2b(src[(size_t)(r0 + ty + i) * C + c0 + tx]);
  __syncthreads();
#pragma unroll
  for (int i = 0; i < 64; i += 4)
    dst[(size_t)(c0 + ty + i) * R + r0 + tx] = tile[tx][ty + i];
}

// ---------------------------------------------------------------------------
// Spatial stats: per (bt_local, h): kvs[16][16] = sum_n kn^T v ; ksum[16]
// ---------------------------------------------------------------------------
__global__ __launch_bounds__(256) void spatial_stats(const u16* __restrict__ qkv,
                                                     float* __restrict__ kvs,
                                                     float* __restrict__ ksum)
{
  __shared__ float sk[512][16];
  __shared__ float sv[512][16];
  const int bt = blockIdx.x;
  const int h = blockIdx.y;
  const int tid = threadIdx.x;
#pragma unroll
  for (int r = 0; r < 2; ++r) {
    int n = tid * 2 + r;
    size_t base = ((size_t)bt * 512 + n) * 384;
    const short8* kp = (const short8*)(qkv + base + 128 + h * 16);
    const short8* vp = (const short8*)(qkv + base + 256 + h * 16);
    short8 kA = kp[0], kB = kp[1], vA = vp[0], vB = vp[1];
    float kf[16], vf[16];
#pragma unroll
    for (int j = 0; j < 8; ++j) {
      kf[j] = b2f((u16)kA[j]); kf[j + 8] = b2f((u16)kB[j]);
      vf[j] = b2f((u16)vA[j]); vf[j + 8] = b2f((u16)vB[j]);
    }
    float s = 0.f;
#pragma unroll
    for (int j = 0; j < 16; ++j) s += kf[j] * kf[j];
    float inv = 1.f / fmaxf(sqrtf(s), 1e-12f);
#pragma unroll
    for (int j = 0; j < 16; ++j) { sk[n][j] = kf[j] * inv; sv[n][j] = vf[j]; }
  }
  __syncthreads();
  const int m = tid >> 4, d = tid & 15;
  float acc = 0.f, ks = 0.f;
  for (int n = 0; n < 512; ++n) {
    float kn = sk[n][m];
    acc = fmaf(kn, sv[n][d], acc);
    if (d == 0) ks += kn;
  }
  size_t o = (size_t)bt * 8 + h;
  kvs[o * 256 + m * 16 + d] = acc;
  if (d == 0) ksum[o * 16 + m] = ks;
}

// ---------------------------------------------------------------------------
// Temporal stats: per (b_local, n): per h: kvt[m][h*16+d] layout ; ksum_t
// ---------------------------------------------------------------------------
__global__ __launch_bounds__(256) void temporal_stats(const u16* __restrict__ qkv,
                                                      float* __restrict__ kvt,
                                                      float* __restrict__ ksum_t)
{
  __shared__ float sk[24][128];
  __shared__ float sv[24][128];
  __shared__ float sinv[24][8];
  const int nn = blockIdx.x, b = blockIdx.y;
  const int tid = threadIdx.x;
  for (int i = tid; i < 24 * 256; i += 256) {
    int t = i >> 8, c = i & 255;
    float val = b2f(qkv[(((size_t)(b * 24 + t) * 512) + nn) * 384 + 128 + c]);
    if (c < 128) sk[t][c] = val;
    else sv[t][c - 128] = val;
  }
  __syncthreads();
  if (tid < 192) {
    int t = tid >> 3, h = tid & 7;
    float s = 0.f;
#pragma unroll
    for (int j = 0; j < 16; ++j) { float v = sk[t][h * 16 + j]; s += v * v; }
    sinv[t][h] = 1.f / fmaxf(sqrtf(s), 1e-12f);
  }
  __syncthreads();
  const int m = tid >> 4, d = tid & 15;
  size_t nb = (size_t)b * 512 + nn;
#pragma unroll
  for (int h = 0; h < 8; ++h) {
    float acc = 0.f, ks = 0.f;
#pragma unroll
    for (int t = 0; t < 24; ++t) {
      float kn = sk[t][h * 16 + m] * sinv[t][h];
      acc = fmaf(kn, sv[t][h * 16 + d], acc);
      if (d == 0) ks += kn;
    }
    // layout: [m][h*16+d] for conflict-free apply-side LDS reads
    kvt[nb * 2048 + m * 128 + h * 16 + d] = acc;
    if (d == 0) ksum_t[(nb * 8 + h) * 16 + m] = ks;
  }
}

// ---------------------------------------------------------------------------
// Apply: per (b_local, n), loop t barrier-free; q/v via L1 broadcast loads.
// waves 0-1: spatial (c<128), waves 2-3: temporal.
// ---------------------------------------------------------------------------
__global__ __launch_bounds__(256) void attn_apply(const u16* __restrict__ qkv,
                                                  const float* __restrict__ kvs,
                                                  const float* __restrict__ kss,
                                                  const float* __restrict__ kvt,
                                                  const float* __restrict__ kst,
                                                  u16* __restrict__ out_cat)
{
  __shared__ float s_kvt[2048];   // [m][h*16+d]
  __shared__ float s_kst[8][16];
  const int nn = blockIdx.x, b = blockIdx.y;
  const int tid = threadIdx.x;
  const size_t nb = (size_t)b * 512 + nn;
  for (int i = tid; i < 2048; i += 256) s_kvt[i] = kvt[nb * 2048 + i];
  if (tid < 128) s_kst[tid >> 4][tid & 15] = kst[nb * 128 + tid];
  __syncthreads();
  const int c = tid;
  const bool temporal = c >= 128;
  const int cl = c & 127;
  const int hh = cl >> 4, d = c & 15;
  const float cnt = temporal ? 24.f : 512.f;
  for (int t = 0; t < 24; ++t) {
    const size_t row = ((size_t)(b * 24 + t) * 512) + nn;
    const u16* qp = qkv + row * 384 + hh * 16;
    short8 q0 = *(const short8*)qp;
    short8 q1 = *(const short8*)(qp + 8);
    float qf[16];
#pragma unroll
    for (int j = 0; j < 8; ++j) {
      qf[j] = b2f((u16)q0[j]);
      qf[j + 8] = b2f((u16)q1[j]);
    }
    float s = 0.f;
#pragma unroll
    for (int j = 0; j < 16; ++j) s += qf[j] * qf[j];
    const float inv = 1.f / fmaxf(sqrtf(s), 1e-12f);
    float acc = 0.f, den = 0.f;
    if (temporal) {
#pragma unroll
      for (int mI = 0; mI < 16; ++mI) {
        float qn = qf[mI] * inv;
        acc = fmaf(qn, s_kvt[mI * 128 + cl], acc);
        den = fmaf(qn, s_kst[hh][mI], den);
      }
    } else {
      const float* Mm = kvs + ((size_t)(b * 24 + t) * 8 + hh) * 256;
      const float* Ks = kss + ((size_t)(b * 24 + t) * 8 + hh) * 16;
#pragma unroll
      for (int mI = 0; mI < 16; ++mI) {
        float qn = qf[mI] * inv;
        acc = fmaf(qn, Mm[mI * 16 + d], acc);
        den = fmaf(qn, Ks[mI], den);
      }
    }
    float vv = b2f(qkv[row * 384 + 256 + cl]);
    out_cat[row * 256 + c] = f2b((acc + cnt * vv) / (den + cnt));
  }
}

// out = LN(a + b); one wave per 128-elem row; optional bf16 copy
__global__ __launch_bounds__(256) void layernorm2(const float* __restrict__ a,
                                                  const float* __restrict__ b,
                                                  const float* __restrict__ g,
                                                  const float* __restrict__ beta,
                                                  float* __restrict__ out32,
                                                  u16* __restrict__ out16)
{
  const int row = blockIdx.x * 4 + (threadIdx.x >> 6);
  const int lane = threadIdx.x & 63;
  const size_t base = (size_t)row * 128;
  float v0 = a[base + lane] + b[base + lane];
  float v1 = a[base + lane + 64] + b[base + lane + 64];
  float s = v0 + v1;
#pragma unroll
  for (int off = 32; off >= 1; off >>= 1) s += __shfl_xor(s, off);
  float mu = s * (1.f / 128.f);
  float d0 = v0 - mu, d1 = v1 - mu;
  float vs = d0 * d0 + d1 * d1;
#pragma unroll
  for (int off = 32; off >= 1; off >>= 1) vs += __shfl_xor(vs, off);
  float rstd = rsqrtf(vs * (1.f / 128.f) + 1e-5f);
  float y0 = d0 * rstd * g[lane] + beta[lane];
  float y1 = d1 * rstd * g[lane + 64] + beta[lane + 64];
  out32[base + lane] = y0;
  out32[base + lane + 64] = y1;
  if (out16) {
    out16[base + lane] = f2b(y0);
    out16[base + lane + 64] = f2b(y1);
  }
}

extern "C" void kernel_launch(void* const* d_in, const int* in_sizes, int n_in,
                              void* d_out, int out_size, void* d_ws, size_t ws_size,
                              hipStream_t stream)
{
  const float* x      = (const float*)d_in[0];
  const float* graph  = (const float*)d_in[1];
  const float* qkv_w0 = (const float*)d_in[2];
  const float* out_w0 = (const float*)d_in[3];
  const float* out_b0 = (const float*)d_in[4];
  const float* pw_w0  = (const float*)d_in[5];
  const float* pw_b0  = (const float*)d_in[6];
  const float* qkv_w1 = (const float*)d_in[7];
  const float* out_w1 = (const float*)d_in[8];
  const float* out_b1 = (const float*)d_in[9];
  const float* pw_w1  = (const float*)d_in[10];
  const float* pw_b1  = (const float*)d_in[11];
  const float* fc1_w  = (const float*)d_in[12];
  const float* fc1_b  = (const float*)d_in[13];
  const float* fc2_w  = (const float*)d_in[14];
  const float* fc2_b  = (const float*)d_in[15];
  const float* ln1_g  = (const float*)d_in[16];
  const float* ln1_b  = (const float*)d_in[17];
  const float* ln2_g  = (const float*)d_in[18];
  const float* ln2_b  = (const float*)d_in[19];
  float* out = (float*)d_out;

  auto al = [](size_t v) { return (v + 255) & ~(size_t)255; };
  const size_t Rb = 12288;  // rows per batch element
  const size_t fixed = al((size_t)Tt * Nn * Nn * 2) + 2 * al((size_t)384 * 128 * 2)
                     + 2 * al((size_t)128 * 256 * 2) + 2 * al((size_t)128 * 128 * 2)
                     + al((size_t)256 * 128 * 2) + al((size_t)128 * 256 * 2);
  const size_t perb = al(Rb * 768) + al(Rb * 512) + 4 * al(Rb * 256) + al(Rb * 512)
                    + al((size_t)Tt * 8 * 256 * 4) + al((size_t)Tt * 8 * 16 * 4)
                    + al((size_t)Nn * 8 * 256 * 4) + al((size_t)Nn * 8 * 16 * 4);
  int CB = 8;
  while (CB > 1 && fixed + (size_t)CB * perb > ws_size) CB >>= 1;
  const size_t Mc = (size_t)CB * Rb;

  char* cur = (char*)d_ws;
  auto alloc = [&](size_t bytes) { char* p = cur; cur += (bytes + 255) & ~(size_t)255; return p; };
  u16* g_b16 = (u16*)alloc((size_t)Tt * Nn * Nn * 2);
  u16* qkvT0 = (u16*)alloc((size_t)384 * 128 * 2);
  u16* qkvT1 = (u16*)alloc((size_t)384 * 128 * 2);
  u16* outT0 = (u16*)alloc((size_t)128 * 256 * 2);
  u16* outT1 = (u16*)alloc((size_t)128 * 256 * 2);
  u16* pwT0  = (u16*)alloc((size_t)128 * 128 * 2);
  u16* pwT1  = (u16*)alloc((size_t)128 * 128 * 2);
  u16* fc1T  = (u16*)alloc((size_t)256 * 128 * 2);
  u16* fc2T  = (u16*)alloc((size_t)128 * 256 * 2);
  u16* qkvb  = (u16*)alloc(Mc * 768);          // reused as h32+h16 later
  u16* catb  = (u16*)alloc(Mc * 512);          // cat / MLP hidden
  u16* x1b   = (u16*)alloc(Mc * 256);          // x1 / att1
  u16* att0  = (u16*)alloc(Mc * 256);
  u16* xb    = (u16*)alloc(Mc * 256);
  u16* xT    = (u16*)alloc(Mc * 256);
  float* glo = (float*)alloc(Mc * 512);        // glo / MLP out
  float* kvs = (float*)alloc((size_t)CB * Tt * 8 * 256 * 4);
  float* kss = (float*)alloc((size_t)CB * Tt * 8 * 16 * 4);
  float* kvt = (float*)alloc((size_t)CB * Nn * 8 * 256 * 4);
  float* kst = (float*)alloc((size_t)CB * Nn * 8 * 16 * 4);

  dim3 blk(256);
  // one-time conversions
  cvt_f32_bf16<<<dim3((Tt * Nn * Nn / 8 + 255) / 256), blk, 0, stream>>>(
      graph, g_b16, (size_t)Tt * Nn * Nn / 8);
  transpose_cvt<<<dim3(6, 2, 1), blk, 0, stream>>>(qkv_w0, qkvT0, 128, 384);
  transpose_cvt<<<dim3(6, 2, 1), blk, 0, stream>>>(qkv_w1, qkvT1, 128, 384);
  transpose_cvt<<<dim3(2, 4, 1), blk, 0, stream>>>(out_w0, outT0, 256, 128);
  transpose_cvt<<<dim3(2, 4, 1), blk, 0, stream>>>(out_w1, outT1, 256, 128);
  transpose_cvt<<<dim3(2, 2, 1), blk, 0, stream>>>(pw_w0, pwT0, 128, 128);
  transpose_cvt<<<dim3(2, 2, 1), blk, 0, stream>>>(pw_w1, pwT1, 128, 128);
  transpose_cvt<<<dim3(4, 2, 1), blk, 0, stream>>>(fc1_w, fc1T, 128, 256);
  transpose_cvt<<<dim3(2, 4, 1), blk, 0, stream>>>(fc2_w, fc2T, 256, 128);

  const int MB = (int)(Mc / 128);
  const int nchunk = Bb / CB;
  for (int c = 0; c < nchunk; ++c) {
    const size_t off = (size_t)c * Mc * 128;
    const float* xc = x + off;
    float* outc = out + off;

    cvt_f32_bf16<<<dim3((unsigned)(Mc * 16 / 256)), blk, 0, stream>>>(xc, xb, Mc * 16);
    transpose_cvt<<<dim3(2, 8, CB * Tt), blk, 0, stream>>>(xc, xT, 512, 128);
    gemm_mfma_graph<<<dim3(1, 4, CB * Tt), blk, 0, stream>>>(g_b16, xT, x1b);

    // ----- layer 0 -----
    gemm_mfma_k<1, 0, 0><<<dim3(3, MB), blk, 0, stream>>>(
        xb, qkvT0, nullptr, qkvb, nullptr, nullptr, 0.f, 384, 128);
    spatial_stats<<<dim3(CB * Tt, Hh), blk, 0, stream>>>(qkvb, kvs, kss);
    temporal_stats<<<dim3(Nn, CB), blk, 0, stream>>>(qkvb, kvt, kst);
    attn_apply<<<dim3(Nn, CB), blk, 0, stream>>>(qkvb, kvs, kss, kvt, kst, catb);
    gemm_mfma_k<1, 0, 0><<<dim3(1, MB), blk, 0, stream>>>(
        catb, outT0, out_b0, att0, nullptr, nullptr, 0.f, 128, 256);
    gemm_mfma_k<0, 0, 1><<<dim3(1, MB), blk, 0, stream>>>(
        xb, pwT0, pw_b0, glo, att0, xc, 1.0f, 128, 128);

    // ----- layer 1 -----
    gemm_mfma_k<1, 0, 0><<<dim3(3, MB), blk, 0, stream>>>(
        x1b, qkvT1, nullptr, qkvb, nullptr, nullptr, 0.f, 384, 128);
    spatial_stats<<<dim3(CB * Tt, Hh), blk, 0, stream>>>(qkvb, kvs, kss);
    temporal_stats<<<dim3(Nn, CB), blk, 0, stream>>>(qkvb, kvt, kst);
    attn_apply<<<dim3(Nn, CB), blk, 0, stream>>>(qkvb, kvs, kss, kvt, kst, catb);
    u16* att1 = x1b;  // x1 consumed; reuse
    gemm_mfma_k<1, 0, 0><<<dim3(1, MB), blk, 0, stream>>>(
        catb, outT1, out_b1, att1, nullptr, nullptr, 0.f, 128, 256);
    gemm_mfma_k<0, 0, 1><<<dim3(1, MB), blk, 0, stream>>>(
        att0, pwT1, pw_b1, glo, att1, glo, 0.01f, 128, 128);

    // h = LN(x + glo) -> h32 (+h16); both alias dead qkv region
    float* h32 = (float*)qkvb;
    u16* h16 = (u16*)((char*)qkvb + Mc * 512);
    layernorm2<<<dim3((unsigned)(Mc / 4)), blk, 0, stream>>>(xc, glo, ln1_g, ln1_b, h32, h16);
    // MLP
    gemm_mfma_k<1, 1, 0><<<dim3(2, MB), blk, 0, stream>>>(
        h16, fc1T, fc1_b, catb, nullptr, nullptr, 0.f, 256, 128);
    gemm_mfma_k<0, 0, 0><<<dim3(1, MB), blk, 0, stream>>>(
        catb, fc2T, fc2_b, glo, nullptr, nullptr, 0.f, 128, 256);
    layernorm2<<<dim3((unsigned)(Mc / 4)), blk, 0, stream>>>(h32, glo, ln2_g, ln2_b, outc, nullptr);
  }

  (void)in_sizes; (void)n_in; (void)out_size;
}

// Round 5
// 723.832 us; speedup vs baseline: 2.4435x; 1.1979x over previous
//
#include <hip/hip_runtime.h>
#include <cstddef>

#define Bb 8
#define Tt 24
#define Nn 512
#define Dd 128
#define Hh 8

typedef unsigned short u16;
using short8 = __attribute__((ext_vector_type(8))) short;
using f32x4  = __attribute__((ext_vector_type(4))) float;

__device__ __forceinline__ float b2f(u16 u) {
  union { unsigned u; float f; } w; w.u = ((unsigned)u) << 16; return w.f;
}
__device__ __forceinline__ u16 f2b(float f) {
  union { float f; unsigned u; } w; w.f = f;
  unsigned r = w.u + 0x7FFFu + ((w.u >> 16) & 1u);
  return (u16)(r >> 16);
}

// ---------------------------------------------------------------------------
// bf16 MFMA GEMM: C[M,N] = A[M,K] @ B[K,N], B given transposed BT[N][K].
// 128x128 tile, BK=32, 256 threads = 4 waves (2x2 of 64x64).
// ---------------------------------------------------------------------------
template <int OUTBF16, int RELU, int PW>
__device__ __forceinline__ void gemm_mfma_body(
    const u16* __restrict__ A, const u16* __restrict__ BT,
    const float* __restrict__ bias, void* __restrict__ Cv,
    const u16* __restrict__ att, const float* __restrict__ base,
    float scale, int N, int K, int m0, int n0)
{
  __shared__ u16 sA[4096];
  __shared__ u16 sB[4096];
  const int tid = threadIdx.x;
  const int l = tid & 63, wid = tid >> 6;
  const int wm = (wid >> 1) << 6, wn = (wid & 1) << 6;
  f32x4 acc[4][4] = {};

  int a_off[4], b_off[4];
#pragma unroll
  for (int i = 0; i < 4; ++i) {
    int ra = wm + i * 16 + (l & 15);
    a_off[i] = ((ra << 6) + ((l >> 4) << 4)) ^ ((ra & 7) << 4);
    int rb = wn + i * 16 + (l & 15);
    b_off[i] = ((rb << 6) + ((l >> 4) << 4)) ^ ((rb & 7) << 4);
  }
  const int r0 = tid >> 2, s0 = tid & 3;
  const int r1 = r0 + 64;
  const int w0 = ((r0 << 6) + (s0 << 4)) ^ ((r0 & 7) << 4);
  const int w1 = ((r1 << 6) + (s0 << 4)) ^ ((r1 & 7) << 4);
  const size_t aR0 = (size_t)(m0 + r0) * K, aR1 = (size_t)(m0 + r1) * K;
  const size_t bR0 = (size_t)(n0 + r0) * K, bR1 = (size_t)(n0 + r1) * K;
  const int ks = s0 * 8;

  for (int k0 = 0; k0 < K; k0 += 32) {
    short8 a0 = *(const short8*)(A + aR0 + k0 + ks);
    short8 a1 = *(const short8*)(A + aR1 + k0 + ks);
    short8 b0 = *(const short8*)(BT + bR0 + k0 + ks);
    short8 b1 = *(const short8*)(BT + bR1 + k0 + ks);
    __syncthreads();
    *(short8*)((char*)sA + w0) = a0;
    *(short8*)((char*)sA + w1) = a1;
    *(short8*)((char*)sB + w0) = b0;
    *(short8*)((char*)sB + w1) = b1;
    __syncthreads();
    short8 af[4], bf_[4];
#pragma unroll
    for (int i = 0; i < 4; ++i) {
      af[i]  = *(const short8*)((const char*)sA + a_off[i]);
      bf_[i] = *(const short8*)((const char*)sB + b_off[i]);
    }
#pragma unroll
    for (int mi = 0; mi < 4; ++mi)
#pragma unroll
      for (int ni = 0; ni < 4; ++ni)
        acc[mi][ni] = __builtin_amdgcn_mfma_f32_16x16x32_bf16(
            af[mi], bf_[ni], acc[mi][ni], 0, 0, 0);
  }

  const int cr = (l >> 4) << 2;
  const int cc = l & 15;
#pragma unroll
  for (int mi = 0; mi < 4; ++mi) {
    int rowb = m0 + wm + mi * 16 + cr;
#pragma unroll
    for (int ni = 0; ni < 4; ++ni) {
      int col = n0 + wn + ni * 16 + cc;
      float bb = bias ? bias[col] : 0.f;
#pragma unroll
      for (int r = 0; r < 4; ++r) {
        float v = acc[mi][ni][r] + bb;
        if (RELU) v = fmaxf(v, 0.f);
        size_t idx = (size_t)(rowb + r) * N + col;
        if (PW) {
          ((float*)Cv)[idx] = base[idx] + b2f(att[idx]) * v * scale;
        } else if (OUTBF16) {
          ((u16*)Cv)[idx] = f2b(v);
        } else {
          ((float*)Cv)[idx] = v;
        }
      }
    }
  }
}

template <int OUTBF16, int RELU, int PW>
__global__ __launch_bounds__(256) void gemm_mfma_k(
    const u16* __restrict__ A, const u16* __restrict__ BT,
    const float* __restrict__ bias, void* __restrict__ C,
    const u16* __restrict__ att, const float* __restrict__ base,
    float scale, int N, int K)
{
  gemm_mfma_body<OUTBF16, RELU, PW>(A, BT, bias, C, att, base, scale, N, K,
                                    blockIdx.y * 128, blockIdx.x * 128);
}

// x1[bt] = graph[t] @ x[bt]
__global__ __launch_bounds__(256) void gemm_mfma_graph(
    const u16* __restrict__ g, const u16* __restrict__ xT, u16* __restrict__ x1)
{
  const int bt = blockIdx.z, t = bt % Tt;
  gemm_mfma_body<1, 0, 0>(g + (size_t)t * Nn * Nn, xT + (size_t)bt * Dd * Nn,
                          nullptr, x1 + (size_t)bt * Nn * Dd, nullptr, nullptr,
                          0.f, Dd, Nn, blockIdx.y * 128, 0);
}

__global__ __launch_bounds__(256) void cvt_f32_bf16(const float* __restrict__ src,
                                                    u16* __restrict__ dst, size_t n8)
{
  size_t i = (size_t)blockIdx.x * 256 + threadIdx.x;
  if (i >= n8) return;
  const float4* s = (const float4*)src;
  float4 u = s[i * 2], v = s[i * 2 + 1];
  short8 o;
  o[0] = (short)f2b(u.x); o[1] = (short)f2b(u.y);
  o[2] = (short)f2b(u.z); o[3] = (short)f2b(u.w);
  o[4] = (short)f2b(v.x); o[5] = (short)f2b(v.y);
  o[6] = (short)f2b(v.z); o[7] = (short)f2b(v.w);
  *(short8*)(dst + i * 8) = o;
}

__global__ __launch_bounds__(256) void transpose_cvt(const float* __restrict__ src,
                                                     u16* __restrict__ dst,
                                                     int R, int C)
{
  __shared__ u16 tile[64][65];
  const int tid = threadIdx.x;
  src += (size_t)blockIdx.z * R * C;
  dst += (size_t)blockIdx.z * R * C;
  const int c0 = blockIdx.x * 64, r0 = blockIdx.y * 64;
  const int tx = tid & 63, ty = tid >> 6;
#pragma unroll
  for (int i = 0; i < 64; i += 4)
    tile[ty + i][tx] = f2b(src[(size_t)(r0 + ty + i) * C + c0 + tx]);
  __syncthreads();
#pragma unroll
  for (int i = 0; i < 64; i += 4)
    dst[(size_t)(c0 + ty + i) * R + r0 + tx] = tile[tx][ty + i];
}

// ---------------------------------------------------------------------------
// Spatial stats via MFMA: per (bt, h): kvs[16][16] = kn^T @ v over n=512.
// LDS: knT/vT [16 dims][512 n] bf16, byte addr ^ ((m&7)<<4).
// 4 waves x 4 K-steps of mfma_16x16x32; ksum via ones-B mfma.
// ---------------------------------------------------------------------------
__global__ __launch_bounds__(256) void spatial_stats(const u16* __restrict__ qkv,
                                                     float* __restrict__ kvs,
                                                     float* __restrict__ ksum)
{
  __shared__ u16 sKT[16 * 512];
  __shared__ u16 sVT[16 * 512];
  __shared__ float red[4][16][16];
  __shared__ float red2[4][16];
  const int bt = blockIdx.x, h = blockIdx.y;
  const int tid = threadIdx.x;

  u16 kr[2][16], vr[2][16];
#pragma unroll
  for (int r = 0; r < 2; ++r) {
    int n = tid * 2 + r;
    size_t base = ((size_t)bt * 512 + n) * 384;
    short8 k0 = *(const short8*)(qkv + base + 128 + h * 16);
    short8 k1 = *(const short8*)(qkv + base + 136 + h * 16);
    short8 v0 = *(const short8*)(qkv + base + 256 + h * 16);
    short8 v1 = *(const short8*)(qkv + base + 264 + h * 16);
    float kf[16];
    float s = 0.f;
#pragma unroll
    for (int j = 0; j < 8; ++j) {
      kf[j] = b2f((u16)k0[j]); kf[j + 8] = b2f((u16)k1[j]);
      vr[r][j] = (u16)v0[j];   vr[r][j + 8] = (u16)v1[j];
      s += kf[j] * kf[j] + kf[j + 8] * kf[j + 8];
    }
    float inv = 1.f / fmaxf(sqrtf(s), 1e-12f);
#pragma unroll
    for (int j = 0; j < 16; ++j) kr[r][j] = f2b(kf[j] * inv);
  }
#pragma unroll
  for (int m = 0; m < 16; ++m) {
    unsigned pk = (unsigned)kr[0][m] | ((unsigned)kr[1][m] << 16);
    unsigned pv = (unsigned)vr[0][m] | ((unsigned)vr[1][m] << 16);
    int wa = ((m << 10) + (tid << 2)) ^ ((m & 7) << 4);
    *(unsigned*)((char*)sKT + wa) = pk;
    *(unsigned*)((char*)sVT + wa) = pv;
  }
  __syncthreads();

  const int l = tid & 63, w = tid >> 6;
  const int fr = l & 15, tq = l >> 4;
  short8 ones;
#pragma unroll
  for (int j = 0; j < 8; ++j) ones[j] = (short)0x3F80;
  f32x4 acc = {}, acs = {};
#pragma unroll
  for (int kk = 0; kk < 4; ++kk) {
    int noff = w * 128 + kk * 32 + tq * 8;
    int ra = ((fr << 10) + (noff << 1)) ^ ((fr & 7) << 4);
    short8 afr = *(const short8*)((const char*)sKT + ra);
    short8 bfr = *(const short8*)((const char*)sVT + ra);
    acc = __builtin_amdgcn_mfma_f32_16x16x32_bf16(afr, bfr, acc, 0, 0, 0);
    acs = __builtin_amdgcn_mfma_f32_16x16x32_bf16(afr, ones, acs, 0, 0, 0);
  }
#pragma unroll
  for (int r = 0; r < 4; ++r) red[w][tq * 4 + r][fr] = acc[r];
  if (fr == 0) {
#pragma unroll
    for (int r = 0; r < 4; ++r) red2[w][tq * 4 + r] = acs[r];
  }
  __syncthreads();
  const size_t o = (size_t)bt * 8 + h;
  {
    int m = tid >> 4, d = tid & 15;
    float s = red[0][m][d] + red[1][m][d] + red[2][m][d] + red[3][m][d];
    kvs[o * 256 + m * 16 + d] = s;
  }
  if (tid < 16) {
    float s = red2[0][tid] + red2[1][tid] + red2[2][tid] + red2[3][tid];
    ksum[o * 16 + tid] = s;
  }
}

// ---------------------------------------------------------------------------
// Temporal stats via MFMA: per (b,n): per h one mfma over t (24 padded to 32).
// LDS: knT/vT [128 c][32 t] bf16, byte addr ^ ((c&3)<<4).
// kvt layout [m][h*16+d] for apply-side conflict-free reads.
// ---------------------------------------------------------------------------
__global__ __launch_bounds__(256) void temporal_stats(const u16* __restrict__ qkv,
                                                      float* __restrict__ kvt,
                                                      float* __restrict__ kst)
{
  __shared__ u16 sKT[128 * 32];
  __shared__ u16 sVT[128 * 32];
  const int nn = blockIdx.x, b = blockIdx.y;
  const int tid = threadIdx.x;
  if (tid < 128) {
    short8 z = {};
    int wa = ((tid << 6) + 48) ^ ((tid & 3) << 4);
    *(short8*)((char*)sKT + wa) = z;
    *(short8*)((char*)sVT + wa) = z;
  }
  for (int idx = tid; idx < 384; idx += 256) {
    int t = idx >> 4, c8 = idx & 15;
    size_t row = ((size_t)(b * 24 + t) * 512) + nn;
    short8 kv = *(const short8*)(qkv + row * 384 + 128 + c8 * 8);
    short8 vv = *(const short8*)(qkv + row * 384 + 256 + c8 * 8);
    float kf[8];
    float ss = 0.f;
#pragma unroll
    for (int j = 0; j < 8; ++j) { kf[j] = b2f((u16)kv[j]); ss += kf[j] * kf[j]; }
    ss += __shfl_xor(ss, 1);
    float inv = 1.f / fmaxf(sqrtf(ss), 1e-12f);
#pragma unroll
    for (int j = 0; j < 8; ++j) {
      int c = c8 * 8 + j;
      int wa = ((c << 6) + (t << 1)) ^ ((c & 3) << 4);
      *(u16*)((char*)sKT + wa) = f2b(kf[j] * inv);
      *(u16*)((char*)sVT + wa) = (u16)vv[j];
    }
  }
  __syncthreads();
  const int l = tid & 63, w = tid >> 6;
  const int fr = l & 15, tq = l >> 4;
  const size_t nb = (size_t)b * 512 + nn;
  short8 ones;
#pragma unroll
  for (int j = 0; j < 8; ++j) ones[j] = (short)0x3F80;
#pragma unroll
  for (int hi = 0; hi < 2; ++hi) {
    int h = w * 2 + hi;
    int c = h * 16 + fr;
    int ra = ((c << 6) + (tq << 4)) ^ ((c & 3) << 4);
    short8 afr = *(const short8*)((const char*)sKT + ra);
    short8 bfr = *(const short8*)((const char*)sVT + ra);
    f32x4 z = {};
    f32x4 acc = __builtin_amdgcn_mfma_f32_16x16x32_bf16(afr, bfr, z, 0, 0, 0);
    f32x4 acs = __builtin_amdgcn_mfma_f32_16x16x32_bf16(afr, ones, z, 0, 0, 0);
#pragma unroll
    for (int r = 0; r < 4; ++r)
      kvt[nb * 2048 + (size_t)(tq * 4 + r) * 128 + h * 16 + fr] = acc[r];
    if (fr == 0) {
#pragma unroll
      for (int r = 0; r < 4; ++r)
        kst[(nb * 8 + h) * 16 + tq * 4 + r] = acs[r];
    }
  }
}

// ---------------------------------------------------------------------------
// Apply: per (b_local, n, t-chunk of 8); barrier-free loop.
// ---------------------------------------------------------------------------
__global__ __launch_bounds__(256) void attn_apply(const u16* __restrict__ qkv,
                                                  const float* __restrict__ kvs,
                                                  const float* __restrict__ kss,
                                                  const float* __restrict__ kvt,
                                                  const float* __restrict__ kst,
                                                  u16* __restrict__ out_cat)
{
  __shared__ float s_kvt[2048];   // [m][h*16+d]
  __shared__ float s_kst[8][16];
  const int nn = blockIdx.x, b = blockIdx.y;
  const int t0 = blockIdx.z * 8;
  const int tid = threadIdx.x;
  const size_t nb = (size_t)b * 512 + nn;
  for (int i = tid; i < 2048; i += 256) s_kvt[i] = kvt[nb * 2048 + i];
  if (tid < 128) s_kst[tid >> 4][tid & 15] = kst[nb * 128 + tid];
  __syncthreads();
  const int c = tid;
  const bool temporal = c >= 128;
  const int cl = c & 127;
  const int hh = cl >> 4, d = c & 15;
  const float cnt = temporal ? 24.f : 512.f;
  for (int t = t0; t < t0 + 8; ++t) {
    const size_t row = ((size_t)(b * 24 + t) * 512) + nn;
    const u16* qp = qkv + row * 384 + hh * 16;
    short8 q0 = *(const short8*)qp;
    short8 q1 = *(const short8*)(qp + 8);
    float qf[16];
#pragma unroll
    for (int j = 0; j < 8; ++j) {
      qf[j] = b2f((u16)q0[j]);
      qf[j + 8] = b2f((u16)q1[j]);
    }
    float s = 0.f;
#pragma unroll
    for (int j = 0; j < 16; ++j) s += qf[j] * qf[j];
    const float inv = 1.f / fmaxf(sqrtf(s), 1e-12f);
    float acc = 0.f, den = 0.f;
    if (temporal) {
#pragma unroll
      for (int mI = 0; mI < 16; ++mI) {
        float qn = qf[mI] * inv;
        acc = fmaf(qn, s_kvt[mI * 128 + cl], acc);
        den = fmaf(qn, s_kst[hh][mI], den);
      }
    } else {
      const float* Mm = kvs + ((size_t)(b * 24 + t) * 8 + hh) * 256;
      const float* Ks = kss + ((size_t)(b * 24 + t) * 8 + hh) * 16;
#pragma unroll
      for (int mI = 0; mI < 16; ++mI) {
        float qn = qf[mI] * inv;
        acc = fmaf(qn, Mm[mI * 16 + d], acc);
        den = fmaf(qn, Ks[mI], den);
      }
    }
    float vv = b2f(qkv[row * 384 + 256 + cl]);
    out_cat[row * 256 + c] = f2b((acc + cnt * vv) / (den + cnt));
  }
}

// out = LN(a + b)
__global__ __launch_bounds__(256) void layernorm2(const float* __restrict__ a,
                                                  const float* __restrict__ b,
                                                  const float* __restrict__ g,
                                                  const float* __restrict__ beta,
                                                  float* __restrict__ out32,
                                                  u16* __restrict__ out16)
{
  const int row = blockIdx.x * 4 + (threadIdx.x >> 6);
  const int lane = threadIdx.x & 63;
  const size_t base = (size_t)row * 128;
  float v0 = a[base + lane] + b[base + lane];
  float v1 = a[base + lane + 64] + b[base + lane + 64];
  float s = v0 + v1;
#pragma unroll
  for (int off = 32; off >= 1; off >>= 1) s += __shfl_xor(s, off);
  float mu = s * (1.f / 128.f);
  float d0 = v0 - mu, d1 = v1 - mu;
  float vs = d0 * d0 + d1 * d1;
#pragma unroll
  for (int off = 32; off >= 1; off >>= 1) vs += __shfl_xor(vs, off);
  float rstd = rsqrtf(vs * (1.f / 128.f) + 1e-5f);
  float y0 = d0 * rstd * g[lane] + beta[lane];
  float y1 = d1 * rstd * g[lane + 64] + beta[lane + 64];
  out32[base + lane] = y0;
  out32[base + lane + 64] = y1;
  if (out16) {
    out16[base + lane] = f2b(y0);
    out16[base + lane + 64] = f2b(y1);
  }
}

extern "C" void kernel_launch(void* const* d_in, const int* in_sizes, int n_in,
                              void* d_out, int out_size, void* d_ws, size_t ws_size,
                              hipStream_t stream)
{
  const float* x      = (const float*)d_in[0];
  const float* graph  = (const float*)d_in[1];
  const float* qkv_w0 = (const float*)d_in[2];
  const float* out_w0 = (const float*)d_in[3];
  const float* out_b0 = (const float*)d_in[4];
  const float* pw_w0  = (const float*)d_in[5];
  const float* pw_b0  = (const float*)d_in[6];
  const float* qkv_w1 = (const float*)d_in[7];
  const float* out_w1 = (const float*)d_in[8];
  const float* out_b1 = (const float*)d_in[9];
  const float* pw_w1  = (const float*)d_in[10];
  const float* pw_b1  = (const float*)d_in[11];
  const float* fc1_w  = (const float*)d_in[12];
  const float* fc1_b  = (const float*)d_in[13];
  const float* fc2_w  = (const float*)d_in[14];
  const float* fc2_b  = (const float*)d_in[15];
  const float* ln1_g  = (const float*)d_in[16];
  const float* ln1_b  = (const float*)d_in[17];
  const float* ln2_g  = (const float*)d_in[18];
  const float* ln2_b  = (const float*)d_in[19];
  float* out = (float*)d_out;

  auto al = [](size_t v) { return (v + 255) & ~(size_t)255; };
  const size_t Rb = 12288;
  const size_t fixed = al((size_t)Tt * Nn * Nn * 2) + 2 * al((size_t)384 * 128 * 2)
                     + 2 * al((size_t)128 * 256 * 2) + 2 * al((size_t)128 * 128 * 2)
                     + al((size_t)256 * 128 * 2) + al((size_t)128 * 256 * 2);
  const size_t perb = al(Rb * 768) + al(Rb * 512) + 4 * al(Rb * 256) + al(Rb * 512)
                    + al((size_t)Tt * 8 * 256 * 4) + al((size_t)Tt * 8 * 16 * 4)
                    + al((size_t)Nn * 8 * 256 * 4) + al((size_t)Nn * 8 * 16 * 4);
  int CB = 8;
  while (CB > 1 && fixed + (size_t)CB * perb > ws_size) CB >>= 1;
  const size_t Mc = (size_t)CB * Rb;

  char* cur = (char*)d_ws;
  auto alloc = [&](size_t bytes) { char* p = cur; cur += (bytes + 255) & ~(size_t)255; return p; };
  u16* g_b16 = (u16*)alloc((size_t)Tt * Nn * Nn * 2);
  u16* qkvT0 = (u16*)alloc((size_t)384 * 128 * 2);
  u16* qkvT1 = (u16*)alloc((size_t)384 * 128 * 2);
  u16* outT0 = (u16*)alloc((size_t)128 * 256 * 2);
  u16* outT1 = (u16*)alloc((size_t)128 * 256 * 2);
  u16* pwT0  = (u16*)alloc((size_t)128 * 128 * 2);
  u16* pwT1  = (u16*)alloc((size_t)128 * 128 * 2);
  u16* fc1T  = (u16*)alloc((size_t)256 * 128 * 2);
  u16* fc2T  = (u16*)alloc((size_t)128 * 256 * 2);
  u16* qkvb  = (u16*)alloc(Mc * 768);
  u16* catb  = (u16*)alloc(Mc * 512);
  u16* x1b   = (u16*)alloc(Mc * 256);
  u16* att0  = (u16*)alloc(Mc * 256);
  u16* xb    = (u16*)alloc(Mc * 256);
  u16* xT    = (u16*)alloc(Mc * 256);
  float* glo = (float*)alloc(Mc * 512);
  float* kvs = (float*)alloc((size_t)CB * Tt * 8 * 256 * 4);
  float* kss = (float*)alloc((size_t)CB * Tt * 8 * 16 * 4);
  float* kvt = (float*)alloc((size_t)CB * Nn * 8 * 256 * 4);
  float* kst = (float*)alloc((size_t)CB * Nn * 8 * 16 * 4);

  dim3 blk(256);
  cvt_f32_bf16<<<dim3((Tt * Nn * Nn / 8 + 255) / 256), blk, 0, stream>>>(
      graph, g_b16, (size_t)Tt * Nn * Nn / 8);
  transpose_cvt<<<dim3(6, 2, 1), blk, 0, stream>>>(qkv_w0, qkvT0, 128, 384);
  transpose_cvt<<<dim3(6, 2, 1), blk, 0, stream>>>(qkv_w1, qkvT1, 128, 384);
  transpose_cvt<<<dim3(2, 4, 1), blk, 0, stream>>>(out_w0, outT0, 256, 128);
  transpose_cvt<<<dim3(2, 4, 1), blk, 0, stream>>>(out_w1, outT1, 256, 128);
  transpose_cvt<<<dim3(2, 2, 1), blk, 0, stream>>>(pw_w0, pwT0, 128, 128);
  transpose_cvt<<<dim3(2, 2, 1), blk, 0, stream>>>(pw_w1, pwT1, 128, 128);
  transpose_cvt<<<dim3(4, 2, 1), blk, 0, stream>>>(fc1_w, fc1T, 128, 256);
  transpose_cvt<<<dim3(2, 4, 1), blk, 0, stream>>>(fc2_w, fc2T, 256, 128);

  const int MB = (int)(Mc / 128);
  const int nchunk = Bb / CB;
  for (int c = 0; c < nchunk; ++c) {
    const size_t off = (size_t)c * Mc * 128;
    const float* xc = x + off;
    float* outc = out + off;

    cvt_f32_bf16<<<dim3((unsigned)(Mc * 16 / 256)), blk, 0, stream>>>(xc, xb, Mc * 16);
    transpose_cvt<<<dim3(2, 8, CB * Tt), blk, 0, stream>>>(xc, xT, 512, 128);
    gemm_mfma_graph<<<dim3(1, 4, CB * Tt), blk, 0, stream>>>(g_b16, xT, x1b);

    // ----- layer 0 -----
    gemm_mfma_k<1, 0, 0><<<dim3(3, MB), blk, 0, stream>>>(
        xb, qkvT0, nullptr, qkvb, nullptr, nullptr, 0.f, 384, 128);
    spatial_stats<<<dim3(CB * Tt, Hh), blk, 0, stream>>>(qkvb, kvs, kss);
    temporal_stats<<<dim3(Nn, CB), blk, 0, stream>>>(qkvb, kvt, kst);
    attn_apply<<<dim3(Nn, CB, 3), blk, 0, stream>>>(qkvb, kvs, kss, kvt, kst, catb);
    gemm_mfma_k<1, 0, 0><<<dim3(1, MB), blk, 0, stream>>>(
        catb, outT0, out_b0, att0, nullptr, nullptr, 0.f, 128, 256);
    gemm_mfma_k<0, 0, 1><<<dim3(1, MB), blk, 0, stream>>>(
        xb, pwT0, pw_b0, glo, att0, xc, 1.0f, 128, 128);

    // ----- layer 1 -----
    gemm_mfma_k<1, 0, 0><<<dim3(3, MB), blk, 0, stream>>>(
        x1b, qkvT1, nullptr, qkvb, nullptr, nullptr, 0.f, 384, 128);
    spatial_stats<<<dim3(CB * Tt, Hh), blk, 0, stream>>>(qkvb, kvs, kss);
    temporal_stats<<<dim3(Nn, CB), blk, 0, stream>>>(qkvb, kvt, kst);
    attn_apply<<<dim3(Nn, CB, 3), blk, 0, stream>>>(qkvb, kvs, kss, kvt, kst, catb);
    u16* att1 = x1b;
    gemm_mfma_k<1, 0, 0><<<dim3(1, MB), blk, 0, stream>>>(
        catb, outT1, out_b1, att1, nullptr, nullptr, 0.f, 128, 256);
    gemm_mfma_k<0, 0, 1><<<dim3(1, MB), blk, 0, stream>>>(
        att0, pwT1, pw_b1, glo, att1, glo, 0.01f, 128, 128);

    float* h32 = (float*)qkvb;
    u16* h16 = (u16*)((char*)qkvb + Mc * 512);
    layernorm2<<<dim3((unsigned)(Mc / 4)), blk, 0, stream>>>(xc, glo, ln1_g, ln1_b, h32, h16);
    gemm_mfma_k<1, 1, 0><<<dim3(2, MB), blk, 0, stream>>>(
        h16, fc1T, fc1_b, catb, nullptr, nullptr, 0.f, 256, 128);
    gemm_mfma_k<0, 0, 0><<<dim3(1, MB), blk, 0, stream>>>(
        catb, fc2T, fc2_b, glo, nullptr, nullptr, 0.f, 128, 256);
    layernorm2<<<dim3((unsigned)(Mc / 4)), blk, 0, stream>>>(h32, glo, ln2_g, ln2_b, outc, nullptr);
  }

  (void)in_sizes; (void)n_in; (void)out_size;
}